// Round 1
// baseline (689.572 us; speedup 1.0000x reference)
//
#include <hip/hip_runtime.h>
#include <stdint.h>

// StraightThroughSubsetSampler: out = khot(top_k(scores/tau + gumbel_noise, k))
//
// Wave-per-row design: 64 lanes hold the row's 8192 sortable-u32 keys in
// registers (128/lane). The kth-largest key is found by a monotone-predicate
// binary search where count(key >= X) is computed as sum of
// popc(ballot(u[e] >= X)) -- 1 v_cmp per element per probe, popcount on the
// SALU pipe. Phase 1 searches the top byte (8 probes over all keys); phase 2
// compacts the boundary byte-bin (typically <= a few hundred keys) into LDS /
// 8 regs per lane and searches the low 24 bits there (24 cheap probes).
// No histograms, no LDS atomics, no barriers in the hot path.
//
// tau is divided with bit-exact IEEE semantics: for power-of-two tau
// (harness: 0.5), x*(1/tau) == x/tau exactly; otherwise fall back to real
// division. Ties at the kth boundary keep lowest column indices (stable
// top_k semantics) via a rare in-register ballot-rank path.

namespace {

constexpr int kN = 8192;
constexpr int kLanes = 64;
constexpr int kVPT = kN / (kLanes * 4);  // 32 float4 groups per lane
constexpr int kEPT = kN / kLanes;        // 128 keys per lane
constexpr int kCap = 512;                // compacted candidate list capacity
constexpr int kLJ = kCap / kLanes;       // 8 list regs per lane

typedef float f32x4 __attribute__((ext_vector_type(4)));

__device__ __forceinline__ uint32_t f2sortable(float x) {
  uint32_t b = __float_as_uint(x);
  // monotonic float->uint: larger float => larger uint
  return (b & 0x80000000u) ? ~b : (b | 0x80000000u);
}

// popcount of mask bits strictly below this lane
__device__ __forceinline__ uint32_t mbcnt64(uint64_t m) {
  return __builtin_amdgcn_mbcnt_hi(
      (uint32_t)(m >> 32), __builtin_amdgcn_mbcnt_lo((uint32_t)m, 0u));
}

__global__ __launch_bounds__(kLanes, 3) void st_topk_khot(
    const float* __restrict__ scores, const float* __restrict__ noise,
    const float* __restrict__ tau_p, const int* __restrict__ k_p,
    float* __restrict__ out) {
  __shared__ uint32_t list[kCap];  // 2 KiB

  const int lane = threadIdx.x;
  const size_t row = blockIdx.x;
  f32x4* o4 = reinterpret_cast<f32x4*>(out + row * (size_t)kN);

  uint32_t k = (uint32_t)k_p[0];
  if (k > (uint32_t)kN) k = (uint32_t)kN;
  if (k == 0u) {
    f32x4 z = {0.0f, 0.0f, 0.0f, 0.0f};
#pragma unroll
    for (int i = 0; i < kVPT; ++i)
      __builtin_nontemporal_store(z, o4 + i * kLanes + lane);
    return;
  }

  const float tau = tau_p[0];
  const f32x4* s4 = reinterpret_cast<const f32x4*>(scores + row * (size_t)kN);
  const f32x4* g4 = reinterpret_cast<const f32x4*>(noise + row * (size_t)kN);

  // ---- load + compute keys (bit-exact vs reference: div, then add) ----
  uint32_t u[kEPT];
  {
    const uint32_t tb = __float_as_uint(tau);
    const uint32_t texp = tb & 0x7F800000u;
    // positive, normal, zero mantissa => exact power of two => x*(1/tau)
    // is IEEE-identical to x/tau.
    const bool pow2 =
        ((tb & 0x807FFFFFu) == 0u) && (texp != 0u) && (texp != 0x7F800000u);
    if (pow2) {
      const float r = 1.0f / tau;  // exact
#pragma unroll
      for (int i = 0; i < kVPT; ++i) {
        f32x4 s = s4[i * kLanes + lane];
        f32x4 g = g4[i * kLanes + lane];
        u[4 * i + 0] = f2sortable(s.x * r + g.x);
        u[4 * i + 1] = f2sortable(s.y * r + g.y);
        u[4 * i + 2] = f2sortable(s.z * r + g.z);
        u[4 * i + 3] = f2sortable(s.w * r + g.w);
      }
    } else {
#pragma unroll
      for (int i = 0; i < kVPT; ++i) {
        f32x4 s = s4[i * kLanes + lane];
        f32x4 g = g4[i * kLanes + lane];
        u[4 * i + 0] = f2sortable(s.x / tau + g.x);
        u[4 * i + 1] = f2sortable(s.y / tau + g.y);
        u[4 * i + 2] = f2sortable(s.z / tau + g.z);
        u[4 * i + 3] = f2sortable(s.w / tau + g.w);
      }
    }
  }

  // count(key >= X) over the whole row: 1 v_cmp per element, SALU popc/add.
  auto probe_all = [&](uint32_t X) -> uint32_t {
    uint32_t c = 0;
#pragma unroll
    for (int e = 0; e < kEPT; ++e)
      c += (uint32_t)__popcll(__ballot(u[e] >= X));
    return c;
  };

  // ---- phase 1: binary search the top byte of the kth-largest key ----
  // invariant: count(>= lo<<24) >= k  >  count(>= hi<<24)
  uint32_t lo = 0, hi = 256;
  uint32_t cge = (uint32_t)kN;  // count at lo<<24 (lo=0 -> all keys)
  uint32_t chi = 0;             // count at hi<<24 (hi=256 -> none)
  while (hi - lo > 1u) {
    const uint32_t mid = (lo + hi) >> 1;
    const uint32_t c = probe_all(mid << 24);
    if (c >= k) {
      lo = mid;
      cge = c;
    } else {
      hi = mid;
      chi = c;
    }
  }
  const uint32_t d0 = lo;
  const uint32_t pfx = d0 << 24;
  const uint32_t cin = cge - chi;  // #keys with top byte == d0 (>= 1)

  // ---- phase 2: binary search the low 24 bits ----
  uint32_t T, cgeT, cgtT;
  if (d0 != 0u && cin <= (uint32_t)kCap) {
    // compact the boundary bin into LDS (zero-padded; 0 < any probed X
    // since d0 >= 1), then into kLJ regs per lane.
#pragma unroll
    for (int j = 0; j < kLJ; ++j) list[j * kLanes + lane] = 0u;
    __syncthreads();
    uint32_t base = 0;
#pragma unroll
    for (int e = 0; e < kEPT; ++e) {
      const bool act = (u[e] >> 24) == d0;
      const uint64_t bal = __ballot(act);
      if (bal) {  // wave-uniform skip; bin is sparse
        if (act) list[base + mbcnt64(bal)] = u[e];
        base += (uint32_t)__popcll(bal);
      }
    }
    __syncthreads();
    uint32_t lj[kLJ];
#pragma unroll
    for (int j = 0; j < kLJ; ++j) lj[j] = list[j * kLanes + lane];

    uint32_t mlo = 0, mhi = 1u << 24;
    uint32_t clo = cge, cgt = chi;
    while (mhi - mlo > 1u) {
      const uint32_t mm = (mlo + mhi) >> 1;
      const uint32_t X = pfx | mm;
      uint32_t c = chi;
#pragma unroll
      for (int j = 0; j < kLJ; ++j)
        c += (uint32_t)__popcll(__ballot(lj[j] >= X));
      if (c >= k) {
        mlo = mm;
        clo = c;
      } else {
        mhi = mm;
        cgt = c;
      }
    }
    T = pfx | mlo;
    cgeT = clo;  // count(>= T)  >= k
    cgtT = cgt;  // count(>  T)  <  k
  } else {
    // rare fallback (d0==0 or oversized bin): probe full registers
    uint32_t mlo = 0, mhi = 1u << 24;
    uint32_t clo = cge, cgt = chi;
    while (mhi - mlo > 1u) {
      const uint32_t mm = (mlo + mhi) >> 1;
      const uint32_t c = probe_all(pfx | mm);
      if (c >= k) {
        mlo = mm;
        clo = c;
      } else {
        mhi = mm;
        cgt = c;
      }
    }
    T = pfx | mlo;
    cgeT = clo;
    cgtT = cgt;
  }

  // ---- rare path: ties at T straddle the boundary; keep lowest cols ----
  if (cgeT != k) {  // wave-uniform
    const uint32_t need = k - cgtT;  // #ties to keep, in column order
    uint32_t base = 0;               // ties seen in earlier groups
#pragma unroll
    for (int i = 0; i < kVPT; ++i) {
      // col(i,lane,c) = i*256 + lane*4 + c -> i-major, lane, then c
      const uint32_t q0 = u[4 * i + 0], q1 = u[4 * i + 1];
      const uint32_t q2 = u[4 * i + 2], q3 = u[4 * i + 3];
      const uint32_t e0 = (q0 == T), e1 = (q1 == T);
      const uint32_t e2 = (q2 == T), e3 = (q3 == T);
      const uint64_t b0 = __ballot(e0), b1 = __ballot(e1);
      const uint64_t b2 = __ballot(e2), b3 = __ballot(e3);
      uint32_t keep0 = (q0 > T), keep1 = (q1 > T);
      uint32_t keep2 = (q2 > T), keep3 = (q3 > T);
      if (b0 | b1 | b2 | b3) {
        const uint32_t below =
            mbcnt64(b0) + mbcnt64(b1) + mbcnt64(b2) + mbcnt64(b3);
        const uint32_t r0 = base + below;
        const uint32_t r1 = r0 + e0;
        const uint32_t r2 = r1 + e1;
        const uint32_t r3 = r2 + e2;
        keep0 |= (e0 && r0 < need);
        keep1 |= (e1 && r1 < need);
        keep2 |= (e2 && r2 < need);
        keep3 |= (e3 && r3 < need);
        base += (uint32_t)(__popcll(b0) + __popcll(b1) + __popcll(b2) +
                           __popcll(b3));
      }
      f32x4 o;
      o.x = keep0 ? 1.0f : 0.0f;
      o.y = keep1 ? 1.0f : 0.0f;
      o.z = keep2 ? 1.0f : 0.0f;
      o.w = keep3 ? 1.0f : 0.0f;
      __builtin_nontemporal_store(o, o4 + i * kLanes + lane);
    }
    return;
  }

  // ---- common path: k-hot = (key >= T) ----
#pragma unroll
  for (int i = 0; i < kVPT; ++i) {
    f32x4 o;
    o.x = (u[4 * i + 0] >= T) ? 1.0f : 0.0f;
    o.y = (u[4 * i + 1] >= T) ? 1.0f : 0.0f;
    o.z = (u[4 * i + 2] >= T) ? 1.0f : 0.0f;
    o.w = (u[4 * i + 3] >= T) ? 1.0f : 0.0f;
    __builtin_nontemporal_store(o, o4 + i * kLanes + lane);
  }
}

}  // namespace

extern "C" void kernel_launch(void* const* d_in, const int* in_sizes, int n_in,
                              void* d_out, int out_size, void* d_ws,
                              size_t ws_size, hipStream_t stream) {
  (void)in_sizes;
  (void)n_in;
  (void)d_ws;
  (void)ws_size;
  (void)out_size;
  const float* scores = (const float*)d_in[0];
  const float* noise = (const float*)d_in[1];
  const float* tau_p = (const float*)d_in[2];
  const int* k_p = (const int*)d_in[3];
  float* out = (float*)d_out;

  hipLaunchKernelGGL(st_topk_khot, dim3(kN), dim3(kLanes), 0, stream, scores,
                     noise, tau_p, k_p, out);
}